// Round 6
// baseline (353.877 us; speedup 1.0000x reference)
//
#include <hip/hip_runtime.h>
#include <math.h>

#define N_NODES 100000
#define N_EDGES 1600000
#define D_IN 256
#define D_H 128
#define D_OUT 32
#define N_PAD 102400
#define NB 196       // ceil(100000/512) buckets of 512 target nodes
#define CAPB 10240   // fixed capacity per bucket (mean 8163, +23 sigma)
#define CHUNK 4096   // edges per bucket-block -> 391 blocks

typedef long long ll;
typedef unsigned int uint;
typedef unsigned short ushort;
typedef unsigned char uchar;
typedef short frag_ab __attribute__((ext_vector_type(8)));   // 8 bf16
typedef float frag_cd __attribute__((ext_vector_type(4)));   // 4 f32

__device__ __forceinline__ ushort f2bf(float f) {            // RNE fp32->bf16
    uint u = __float_as_uint(f);
    u += 0x7FFFu + ((u >> 16) & 1u);
    return (ushort)(u >> 16);
}
__device__ __forceinline__ float bfl(uint u) { return __uint_as_float(u << 16); }
__device__ __forceinline__ float bfh(uint u) { return __uint_as_float(u & 0xFFFF0000u); }
__device__ __forceinline__ uint packbf(float a, float b) {
    return (uint)f2bf(a) | ((uint)f2bf(b) << 16);
}

// ---- tiny prep: zero gcur + transpose/pack weights
__global__ __launch_bounds__(256) void k_prep(const float* __restrict__ W1,
                                              const float* __restrict__ W2,
                                              ushort* __restrict__ w1t,
                                              ushort* __restrict__ w2t,
                                              int* __restrict__ gcur) {
    int gi = blockIdx.x * 256 + threadIdx.x;
    if (blockIdx.x == 0) gcur[threadIdx.x] = 0;   // 256 >= NB
    if (gi < D_IN * D_H) {
        int k = gi >> 7, nn = gi & 127;
        w1t[nn * D_IN + k] = f2bf(W1[gi]);
    } else if (gi < D_IN * D_H + D_H * D_OUT) {
        int j = gi - D_IN * D_H;
        int k = j >> 5, nn = j & 31;
        w2t[nn * D_H + k] = f2bf(W2[j]);
    }
}

// ---- fused dispatch (R2-proven): blocks [0,GA) = bucket partition (LDS
//      two-phase + staged coalesced emission), [GA,GA+GG) = GEMM1.
//      Contiguous role split (XCD = bid % 8; parity split partitions the machine).
//      NOTE (R4 lesson): global-atomic/scattered-store variants are 3x worse —
//      memory-side RMW serialization + loss of L2 write-combining.
__global__ __launch_bounds__(256, 3) void k_fused(const int* __restrict__ row,
                                                  const int* __restrict__ col,
                                                  int* __restrict__ gcur,
                                                  uint* __restrict__ pairs,
                                                  const float* __restrict__ x,
                                                  const ushort* __restrict__ w1t,
                                                  ushort* __restrict__ hxs,
                                                  int n, int e) {
    __shared__ int cnt[NB];      // counts, then phase-2 cursors
    __shared__ int lofs[NB];     // local sorted offsets
    __shared__ int lstart[NB];   // claimed global run starts
    __shared__ int sc[256];      // scan temp
    __shared__ uint spair[CHUNK];
    __shared__ uchar sbuck[CHUNK];
    const int t = threadIdx.x;
    const int GA = (e + CHUNK - 1) / CHUNK;
    const int bid = blockIdx.x;

    if (bid < GA) {
        // ----- bucket partition for edge chunk `bid` -----
        if (t < NB) cnt[t] = 0;
        __syncthreads();
        const int base = bid * CHUNK;
        const int end = min(base + CHUNK, e);
        const int valid = end - base;
        // cache this thread's (<=16) edges in registers; statically indexed
        int rs[16], cs[16];
#pragma unroll
        for (int j = 0; j < 16; j++) {
            int idx = base + t + j * 256;
            bool ok = idx < end;
            int c = ok ? col[idx] : 0;
            rs[j] = ok ? row[idx] : 0;
            cs[j] = ok ? c : -1;
            if (ok) atomicAdd(&cnt[c >> 9], 1);
        }
        __syncthreads();
        int v = (t < NB) ? cnt[t] : 0;
        sc[t] = v;
        __syncthreads();
        for (int o = 1; o < 256; o <<= 1) {
            int u2 = (t >= o) ? sc[t - o] : 0;
            __syncthreads();
            sc[t] += u2;
            __syncthreads();
        }
        if (t < NB) {
            lofs[t] = sc[t] - v;
            lstart[t] = (v > 0) ? atomicAdd(&gcur[t], v) : 0;
            cnt[t] = 0;  // reuse as local cursor
        }
        __syncthreads();
#pragma unroll
        for (int j = 0; j < 16; j++) {
            int c = cs[j];
            if (c >= 0) {
                int b = c >> 9;
                int pos = lofs[b] + atomicAdd(&cnt[b], 1);
                spair[pos] = ((uint)rs[j] << 9) | (uint)(c & 511);
                sbuck[pos] = (uchar)b;
            }
        }
        __syncthreads();
        for (int i = t; i < valid; i += 256) {   // bucket-contiguous coalesced emission
            int b = sbuck[i];
            int rel = lstart[b] + (i - lofs[b]);
            if (rel < CAPB) pairs[b * CAPB + rel] = spair[i];
        }
    } else {
        // ----- GEMM1 (MFMA, LDS-free): hxs = bf16( x @ W1 )  (NO dinv scale) -----
        const int id = bid - GA;
        const int wv = t >> 6, lane = t & 63;
        const int lm = lane & 15, quad = lane >> 4;
        const int base = id * 128 + wv * 32;

        frag_cd acc[2][8];
#pragma unroll
        for (int mt = 0; mt < 2; mt++)
#pragma unroll
            for (int nt = 0; nt < 8; nt++) acc[mt][nt] = (frag_cd){0.f, 0.f, 0.f, 0.f};

        const float4* xr[2];
#pragma unroll
        for (int mt = 0; mt < 2; mt++) {
            int node = base + mt * 16 + lm;
            xr[mt] = (const float4*)(x + (ll)min(node, n - 1) * D_IN);
        }

#pragma unroll
        for (int ks = 0; ks < 8; ks++) {
            frag_ab a[2];
#pragma unroll
            for (int mt = 0; mt < 2; mt++) {
                float4 v0 = xr[mt][ks * 8 + quad * 2];
                float4 v1 = xr[mt][ks * 8 + quad * 2 + 1];
                uint* ap = (uint*)&a[mt];
                ap[0] = packbf(v0.x, v0.y);
                ap[1] = packbf(v0.z, v0.w);
                ap[2] = packbf(v1.x, v1.y);
                ap[3] = packbf(v1.z, v1.w);
            }
#pragma unroll
            for (int nt = 0; nt < 8; nt++) {
                frag_ab b = *(const frag_ab*)&w1t[(nt * 16 + lm) * D_IN + ks * 32 + quad * 8];
#pragma unroll
                for (int mt = 0; mt < 2; mt++)
                    acc[mt][nt] = __builtin_amdgcn_mfma_f32_16x16x32_bf16(
                        a[mt], b, acc[mt][nt], 0, 0, 0);
            }
        }

#pragma unroll
        for (int mt = 0; mt < 2; mt++) {
#pragma unroll
            for (int r = 0; r < 4; r++) {
                int node = base + mt * 16 + quad * 4 + r;
                if (node < n) {
#pragma unroll
                    for (int nt = 0; nt < 8; nt++)
                        hxs[(ll)node * D_H + nt * 16 + lm] = f2bf(acc[mt][nt][r]);
                }
            }
        }
    }
}

// ---- pass B: one block per bucket; 1024 threads (was 512: 1 block/CU means
//      occupancy was capped at 25% with 16 serialized trips/phase — doubling
//      threads doubles waves/CU and halves every phase's trip count).
__global__ __launch_bounds__(1024) void k_fillB(const uint* __restrict__ pairs,
                                                const int* __restrict__ gcur,
                                                int* __restrict__ deg,
                                                int* __restrict__ rp,
                                                float* __restrict__ dinv,
                                                int* __restrict__ csr_src, int n) {
    __shared__ int scsr[CAPB];   // 40 KB staged csr for this bucket
    __shared__ int hcnt[512];    // per-node in-degree (LDS histogram)
    __shared__ int cur[512];     // scatter cursors
    __shared__ int ssum[512];
    const int b = blockIdx.x, t = threadIdx.x;
    const int node0 = b << 9;
    if (t < 512) hcnt[t] = 0;
    __syncthreads();
    const int cnt = min(gcur[b], CAPB);
    const uint* pr = pairs + b * CAPB;
    for (int i = t; i < cnt; i += 1024) atomicAdd(&hcnt[pr[i] & 511], 1);
    __syncthreads();
    if (t < 512) ssum[t] = hcnt[t];
    __syncthreads();
    for (int o = 1; o < 512; o <<= 1) {
        int u2 = (t < 512 && t >= o) ? ssum[t - o] : 0;
        __syncthreads();
        if (t < 512) ssum[t] += u2;
        __syncthreads();
    }
    if (t < 512) {
        int d = hcnt[t];
        int excl = ssum[t] - d;
        cur[t] = excl;
        int vv = node0 + t;
        if (vv < n) {
            rp[vv] = b * CAPB + excl;
            deg[vv] = d;
            dinv[vv] = rsqrtf((float)(1 + d));
        }
    }
    __syncthreads();
    for (int i = t; i < cnt; i += 1024) {
        uint pp = pr[i];
        int pos = atomicAdd(&cur[pp & 511], 1);
        if (pos < CAPB) scsr[pos] = (int)(pp >> 9);
    }
    __syncthreads();
    for (int i = t; i < cnt; i += 1024)   // coalesced contiguous write
        csr_src[b * CAPB + i] = scsr[i];
}

// ---- layer-1 gather + FUSED layer-2 GEMM: block = 16 nodes (4 waves x 4 nodes).
//      Gather inner loop unrolled 16-deep (static indexing -> registers): mean
//      deg ~16.3, so a typical node issues ALL its csr/dinv/row loads in one
//      burst — 2x the in-flight loads of the old 8-unroll (latency-bound fix).
__global__ __launch_bounds__(256) void k_agg1f(const uint* __restrict__ hxs,
                                               const int* __restrict__ csr_src,
                                               const int* __restrict__ rp,
                                               const int* __restrict__ deg,
                                               const float* __restrict__ dinv,
                                               const float* __restrict__ b1,
                                               const ushort* __restrict__ w2t,
                                               ushort* __restrict__ hx2s, int n) {
    __shared__ uint lds_h[16 * 68];   // 16 h-rows of 64 uints, stride 68 (bank-spread)
    const int t = threadIdx.x;
    const int w = t >> 6, lane = t & 63;
    const int lm = lane & 15, quad = lane >> 4;
    const int nbase = blockIdx.x * 16;

    float2 bb = ((const float2*)b1)[lane];
#pragma unroll
    for (int q = 0; q < 4; q++) {
        int v = nbase + w * 4 + q;
        float dv = dinv[v];
        uint u = hxs[v * 64 + lane];
        float a0 = dv * bfl(u), a1 = dv * bfh(u);   // self-loop term
        int s = rp[v], e = s + deg[v];
        int i = s;
        for (; i + 15 < e; i += 16) {
            int ss[16]; float nn[16]; uint uu[16];
#pragma unroll
            for (int j = 0; j < 16; j++) ss[j] = csr_src[i + j];
#pragma unroll
            for (int j = 0; j < 16; j++) nn[j] = dinv[ss[j]];
#pragma unroll
            for (int j = 0; j < 16; j++) uu[j] = hxs[ss[j] * 64 + lane];
#pragma unroll
            for (int j = 0; j < 16; j++) {
                a0 = fmaf(nn[j], bfl(uu[j]), a0);
                a1 = fmaf(nn[j], bfh(uu[j]), a1);
            }
        }
        for (; i + 3 < e; i += 4) {
            int ss[4]; float nn[4]; uint uu[4];
#pragma unroll
            for (int j = 0; j < 4; j++) ss[j] = csr_src[i + j];
#pragma unroll
            for (int j = 0; j < 4; j++) nn[j] = dinv[ss[j]];
#pragma unroll
            for (int j = 0; j < 4; j++) uu[j] = hxs[ss[j] * 64 + lane];
#pragma unroll
            for (int j = 0; j < 4; j++) {
                a0 = fmaf(nn[j], bfl(uu[j]), a0);
                a1 = fmaf(nn[j], bfh(uu[j]), a1);
            }
        }
        for (; i < e; i++) {
            int s0 = csr_src[i];
            float n0 = dinv[s0];
            uint u0 = hxs[s0 * 64 + lane];
            a0 = fmaf(n0, bfl(u0), a0);
            a1 = fmaf(n0, bfh(u0), a1);
        }
        lds_h[(w * 4 + q) * 68 + lane] = packbf(fmaxf(fmaf(dv, a0, bb.x), 0.f),
                                                fmaxf(fmaf(dv, a1, bb.y), 0.f));
    }
    __syncthreads();

    if (w < 2) {   // waves 0,1: y[16 nodes][16 j] each (j-half = w)
        frag_cd acc = (frag_cd){0.f, 0.f, 0.f, 0.f};
#pragma unroll
        for (int c = 0; c < 4; c++) {   // k chunks of 32
            frag_ab a = *(const frag_ab*)&lds_h[lm * 68 + 16 * c + 4 * quad];
            frag_ab b = *(const frag_ab*)&w2t[(w * 16 + lm) * D_H + c * 32 + quad * 8];
            acc = __builtin_amdgcn_mfma_f32_16x16x32_bf16(a, b, acc, 0, 0, 0);
        }
#pragma unroll
        for (int r = 0; r < 4; r++) {
            int node = nbase + quad * 4 + r;
            float dv = dinv[node];
            hx2s[node * D_OUT + w * 16 + lm] = f2bf(acc[r] * dv);
        }
    }
}

// ---- layer-2 gather + bias + log_softmax: 16 lanes per node; 16-deep unroll.
__global__ __launch_bounds__(256) void k_agg2(const uint* __restrict__ hx2s,
                                              const int* __restrict__ csr_src,
                                              const int* __restrict__ rp,
                                              const int* __restrict__ deg,
                                              const float* __restrict__ dinv,
                                              const float* __restrict__ b2,
                                              float2* __restrict__ out, int n) {
    int v = blockIdx.x * 16 + (threadIdx.x >> 4);
    if (v >= n) return;
    int l16 = threadIdx.x & 15;
    uint u = hx2s[v * 16 + l16];
    float a0 = bfl(u), a1 = bfh(u);
    int s = rp[v], e = s + deg[v];
    int i = s;
    for (; i + 15 < e; i += 16) {
        int ss[16]; uint uu[16];
#pragma unroll
        for (int j = 0; j < 16; j++) ss[j] = csr_src[i + j];
#pragma unroll
        for (int j = 0; j < 16; j++) uu[j] = hx2s[ss[j] * 16 + l16];
#pragma unroll
        for (int j = 0; j < 16; j++) { a0 += bfl(uu[j]); a1 += bfh(uu[j]); }
    }
    for (; i + 3 < e; i += 4) {
        int ss[4]; uint uu[4];
#pragma unroll
        for (int j = 0; j < 4; j++) ss[j] = csr_src[i + j];
#pragma unroll
        for (int j = 0; j < 4; j++) uu[j] = hx2s[ss[j] * 16 + l16];
#pragma unroll
        for (int j = 0; j < 4; j++) { a0 += bfl(uu[j]); a1 += bfh(uu[j]); }
    }
    for (; i < e; i++) {
        uint u0 = hx2s[csr_src[i] * 16 + l16];
        a0 += bfl(u0);
        a1 += bfh(u0);
    }
    float dv = dinv[v];
    float2 bb = ((const float2*)b2)[l16];
    float t0 = fmaf(dv, a0, bb.x), t1 = fmaf(dv, a1, bb.y);
    float mx = fmaxf(t0, t1);
#pragma unroll
    for (int m = 8; m >= 1; m >>= 1) mx = fmaxf(mx, __shfl_xor(mx, m));
    float sum = __expf(t0 - mx) + __expf(t1 - mx);
#pragma unroll
    for (int m = 8; m >= 1; m >>= 1) sum += __shfl_xor(sum, m);
    float lse = mx + __logf(sum);
    out[v * 16 + l16] = make_float2(t0 - lse, t1 - lse);
}

extern "C" void kernel_launch(void* const* d_in, const int* in_sizes, int n_in,
                              void* d_out, int out_size, void* d_ws, size_t ws_size,
                              hipStream_t stream) {
    const float* x  = (const float*)d_in[0];
    const float* W1 = (const float*)d_in[1];
    const float* b1 = (const float*)d_in[2];
    const float* W2 = (const float*)d_in[3];
    const float* b2 = (const float*)d_in[4];
    const int*   ei = (const int*)d_in[5];
    const int* row = ei;
    const int* col = ei + N_EDGES;

    // ws layout (4B words): deg[N_PAD] | gcur[256] | rp[N_PAD] | dinv[N_PAD] |
    //   csr_src[NB*CAPB] | pairs[NB*CAPB] | w1t | w2t | hxs | (h unused) | hx2s
    int*    ws_i    = (int*)d_ws;
    int*    deg     = ws_i;
    int*    gcur    = ws_i + N_PAD;
    int*    rp      = ws_i + N_PAD + 256;
    float*  dinv    = (float*)(ws_i + 2 * N_PAD + 256);
    int*    csr_src = ws_i + 3 * N_PAD + 256;
    uint*   pairs   = (uint*)(csr_src + NB * CAPB);
    ushort* w1t     = (ushort*)(pairs + NB * CAPB);
    ushort* w2t     = w1t + D_IN * D_H;
    ushort* hxs     = w2t + D_H * D_OUT;
    ushort* h_unused= hxs + (ll)N_NODES * D_H;
    ushort* hx2s    = h_unused + (ll)N_NODES * D_H;

    const int n = N_NODES, e = N_EDGES;

    // zero gcur + pack weights (no deg memset needed: fillB writes deg itself)
    k_prep<<<(D_IN * D_H + D_H * D_OUT + 255) / 256, 256, 0, stream>>>(W1, W2, w1t, w2t, gcur);

    // bucket partition (blocks [0,GA)) + GEMM1 (blocks [GA,GA+GG)), co-resident,
    // contiguous split so both roles spread across all 8 XCDs.
    const int GA = (e + CHUNK - 1) / CHUNK;
    const int GG = (n + 127) / 128;
    k_fused<<<GA + GG, 256, 0, stream>>>(row, col, gcur, pairs, x, w1t, hxs, n, e);

    k_fillB<<<NB, 1024, 0, stream>>>(pairs, gcur, deg, rp, dinv, csr_src, n);
    // agg1 + gemm2 fused: 16 nodes per block (100000 % 16 == 0 -> 6250 blocks)
    k_agg1f<<<n / 16, 256, 0, stream>>>((const uint*)hxs, csr_src, rp, deg, dinv, b1,
                                        w2t, hx2s, n);
    k_agg2<<<(n + 15) / 16, 256, 0, stream>>>((const uint*)hx2s, csr_src, rp, deg, dinv, b2,
                                              (float2*)d_out, n);
}

// Round 7
// 325.789 us; speedup vs baseline: 1.0862x; 1.0862x over previous
//
#include <hip/hip_runtime.h>
#include <math.h>

#define N_NODES 100000
#define N_EDGES 1600000
#define D_IN 256
#define D_H 128
#define D_OUT 32
#define N_PAD 102400
#define NB 196       // ceil(100000/512) buckets of 512 target nodes
#define CAPB 10240   // fixed capacity per bucket (mean 8163, +23 sigma)
#define CHUNK 4096   // edges per bucket-block -> 391 blocks

typedef long long ll;
typedef unsigned int uint;
typedef unsigned short ushort;
typedef unsigned char uchar;
typedef short frag_ab __attribute__((ext_vector_type(8)));   // 8 bf16
typedef float frag_cd __attribute__((ext_vector_type(4)));   // 4 f32

__device__ __forceinline__ ushort f2bf(float f) {            // RNE fp32->bf16
    uint u = __float_as_uint(f);
    u += 0x7FFFu + ((u >> 16) & 1u);
    return (ushort)(u >> 16);
}
__device__ __forceinline__ float bfl(uint u) { return __uint_as_float(u << 16); }
__device__ __forceinline__ float bfh(uint u) { return __uint_as_float(u & 0xFFFF0000u); }
__device__ __forceinline__ uint packbf(float a, float b) {
    return (uint)f2bf(a) | ((uint)f2bf(b) << 16);
}

// ---- tiny prep: zero gcur + transpose/pack weights
__global__ __launch_bounds__(256) void k_prep(const float* __restrict__ W1,
                                              const float* __restrict__ W2,
                                              ushort* __restrict__ w1t,
                                              ushort* __restrict__ w2t,
                                              int* __restrict__ gcur) {
    int gi = blockIdx.x * 256 + threadIdx.x;
    if (blockIdx.x == 0) gcur[threadIdx.x] = 0;   // 256 >= NB
    if (gi < D_IN * D_H) {
        int k = gi >> 7, nn = gi & 127;
        w1t[nn * D_IN + k] = f2bf(W1[gi]);
    } else if (gi < D_IN * D_H + D_H * D_OUT) {
        int j = gi - D_IN * D_H;
        int k = j >> 5, nn = j & 31;
        w2t[nn * D_H + k] = f2bf(W2[j]);
    }
}

// ---- fused dispatch (R2-proven): blocks [0,GA) = bucket partition (LDS
//      two-phase + staged coalesced emission), [GA,GA+GG) = GEMM1.
//      Contiguous role split (XCD = bid % 8; parity split partitions the machine).
//      R4 lesson: global-atomic variants are 3x worse (memory-side RMW).
__global__ __launch_bounds__(256, 3) void k_fused(const int* __restrict__ row,
                                                  const int* __restrict__ col,
                                                  int* __restrict__ gcur,
                                                  uint* __restrict__ pairs,
                                                  const float* __restrict__ x,
                                                  const ushort* __restrict__ w1t,
                                                  ushort* __restrict__ hxs,
                                                  int n, int e) {
    __shared__ int cnt[NB];      // counts, then phase-2 cursors
    __shared__ int lofs[NB];     // local sorted offsets
    __shared__ int lstart[NB];   // claimed global run starts
    __shared__ int sc[256];      // scan temp
    __shared__ uint spair[CHUNK];
    __shared__ uchar sbuck[CHUNK];
    const int t = threadIdx.x;
    const int GA = (e + CHUNK - 1) / CHUNK;
    const int bid = blockIdx.x;

    if (bid < GA) {
        // ----- bucket partition for edge chunk `bid` -----
        if (t < NB) cnt[t] = 0;
        __syncthreads();
        const int base = bid * CHUNK;
        const int end = min(base + CHUNK, e);
        const int valid = end - base;
        // cache this thread's (<=16) edges in registers; statically indexed
        int rs[16], cs[16];
#pragma unroll
        for (int j = 0; j < 16; j++) {
            int idx = base + t + j * 256;
            bool ok = idx < end;
            int c = ok ? col[idx] : 0;
            rs[j] = ok ? row[idx] : 0;
            cs[j] = ok ? c : -1;
            if (ok) atomicAdd(&cnt[c >> 9], 1);
        }
        __syncthreads();
        int v = (t < NB) ? cnt[t] : 0;
        sc[t] = v;
        __syncthreads();
        for (int o = 1; o < 256; o <<= 1) {
            int u2 = (t >= o) ? sc[t - o] : 0;
            __syncthreads();
            sc[t] += u2;
            __syncthreads();
        }
        if (t < NB) {
            lofs[t] = sc[t] - v;
            lstart[t] = (v > 0) ? atomicAdd(&gcur[t], v) : 0;
            cnt[t] = 0;  // reuse as local cursor
        }
        __syncthreads();
#pragma unroll
        for (int j = 0; j < 16; j++) {
            int c = cs[j];
            if (c >= 0) {
                int b = c >> 9;
                int pos = lofs[b] + atomicAdd(&cnt[b], 1);
                spair[pos] = ((uint)rs[j] << 9) | (uint)(c & 511);
                sbuck[pos] = (uchar)b;
            }
        }
        __syncthreads();
        for (int i = t; i < valid; i += 256) {   // bucket-contiguous coalesced emission
            int b = sbuck[i];
            int rel = lstart[b] + (i - lofs[b]);
            if (rel < CAPB) pairs[b * CAPB + rel] = spair[i];
        }
    } else {
        // ----- GEMM1 (MFMA, LDS-free): hxs = bf16( x @ W1 )  (NO dinv scale) -----
        const int id = bid - GA;
        const int wv = t >> 6, lane = t & 63;
        const int lm = lane & 15, quad = lane >> 4;
        const int base = id * 128 + wv * 32;

        frag_cd acc[2][8];
#pragma unroll
        for (int mt = 0; mt < 2; mt++)
#pragma unroll
            for (int nt = 0; nt < 8; nt++) acc[mt][nt] = (frag_cd){0.f, 0.f, 0.f, 0.f};

        const float4* xr[2];
#pragma unroll
        for (int mt = 0; mt < 2; mt++) {
            int node = base + mt * 16 + lm;
            xr[mt] = (const float4*)(x + (ll)min(node, n - 1) * D_IN);
        }

#pragma unroll
        for (int ks = 0; ks < 8; ks++) {
            frag_ab a[2];
#pragma unroll
            for (int mt = 0; mt < 2; mt++) {
                float4 v0 = xr[mt][ks * 8 + quad * 2];
                float4 v1 = xr[mt][ks * 8 + quad * 2 + 1];
                uint* ap = (uint*)&a[mt];
                ap[0] = packbf(v0.x, v0.y);
                ap[1] = packbf(v0.z, v0.w);
                ap[2] = packbf(v1.x, v1.y);
                ap[3] = packbf(v1.z, v1.w);
            }
#pragma unroll
            for (int nt = 0; nt < 8; nt++) {
                frag_ab b = *(const frag_ab*)&w1t[(nt * 16 + lm) * D_IN + ks * 32 + quad * 8];
#pragma unroll
                for (int mt = 0; mt < 2; mt++)
                    acc[mt][nt] = __builtin_amdgcn_mfma_f32_16x16x32_bf16(
                        a[mt], b, acc[mt][nt], 0, 0, 0);
            }
        }

#pragma unroll
        for (int mt = 0; mt < 2; mt++) {
#pragma unroll
            for (int r = 0; r < 4; r++) {
                int node = base + mt * 16 + quad * 4 + r;
                if (node < n) {
#pragma unroll
                    for (int nt = 0; nt < 8; nt++)
                        hxs[(ll)node * D_H + nt * 16 + lm] = f2bf(acc[mt][nt][r]);
                }
            }
        }
    }
}

// ---- pass B (R2-proven, 512 threads): LDS histogram reproduces deg, scan,
//      LDS-staged csr + coalesced write. (1024-thread variant unproven; reverted.)
__global__ __launch_bounds__(512) void k_fillB(const uint* __restrict__ pairs,
                                               const int* __restrict__ gcur,
                                               int* __restrict__ deg,
                                               int* __restrict__ rp,
                                               float* __restrict__ dinv,
                                               int* __restrict__ csr_src, int n) {
    __shared__ int scsr[CAPB];   // 40 KB staged csr for this bucket
    __shared__ int hcnt[512];    // per-node in-degree (LDS histogram)
    __shared__ int cur[512];     // scatter cursors
    __shared__ int ssum[512];
    const int b = blockIdx.x, t = threadIdx.x;
    const int node0 = b << 9;
    hcnt[t] = 0;
    __syncthreads();
    const int cnt = min(gcur[b], CAPB);
    const uint* pr = pairs + b * CAPB;
    for (int i = t; i < cnt; i += 512) atomicAdd(&hcnt[pr[i] & 511], 1);
    __syncthreads();
    int d = hcnt[t];
    ssum[t] = d;
    __syncthreads();
    for (int o = 1; o < 512; o <<= 1) {
        int u2 = (t >= o) ? ssum[t - o] : 0;
        __syncthreads();
        ssum[t] += u2;
        __syncthreads();
    }
    int excl = ssum[t] - d;
    cur[t] = excl;
    {
        int vv = node0 + t;
        if (vv < n) {
            rp[vv] = b * CAPB + excl;
            deg[vv] = d;
            dinv[vv] = rsqrtf((float)(1 + d));
        }
    }
    __syncthreads();
    for (int i = t; i < cnt; i += 512) {
        uint pp = pr[i];
        int pos = atomicAdd(&cur[pp & 511], 1);
        if (pos < CAPB) scsr[pos] = (int)(pp >> 9);
    }
    __syncthreads();
    for (int i = t; i < cnt; i += 512)   // coalesced contiguous write
        csr_src[b * CAPB + i] = scsr[i];
}

// ---- layer-1 gather + FUSED layer-2 GEMM: block = 16 nodes (4 waves x 4 nodes).
//      8-deep unroll (R6 lesson: 16-deep per-wave bursts thrash L2, +23us).
//      __launch_bounds__(256,8): request full 8 waves/EU co-residency — adds
//      wave-level outstanding misses without enlarging per-wave line footprint.
__global__ __launch_bounds__(256, 8) void k_agg1f(const uint* __restrict__ hxs,
                                                  const int* __restrict__ csr_src,
                                                  const int* __restrict__ rp,
                                                  const int* __restrict__ deg,
                                                  const float* __restrict__ dinv,
                                                  const float* __restrict__ b1,
                                                  const ushort* __restrict__ w2t,
                                                  ushort* __restrict__ hx2s, int n) {
    __shared__ uint lds_h[16 * 68];   // 16 h-rows of 64 uints, stride 68 (bank-spread)
    const int t = threadIdx.x;
    const int w = t >> 6, lane = t & 63;
    const int lm = lane & 15, quad = lane >> 4;
    const int nbase = blockIdx.x * 16;

    float2 bb = ((const float2*)b1)[lane];
#pragma unroll
    for (int q = 0; q < 4; q++) {
        int v = nbase + w * 4 + q;
        float dv = dinv[v];
        uint u = hxs[v * 64 + lane];
        float a0 = dv * bfl(u), a1 = dv * bfh(u);   // self-loop term
        int s = rp[v], e = s + deg[v];
        int i = s;
        for (; i + 7 < e; i += 8) {
            int s0 = csr_src[i], s1 = csr_src[i + 1];
            int s2 = csr_src[i + 2], s3 = csr_src[i + 3];
            int s4 = csr_src[i + 4], s5 = csr_src[i + 5];
            int s6 = csr_src[i + 6], s7 = csr_src[i + 7];
            float n0 = dinv[s0], n1 = dinv[s1], n2 = dinv[s2], n3 = dinv[s3];
            float n4 = dinv[s4], n5 = dinv[s5], n6 = dinv[s6], n7 = dinv[s7];
            uint u0 = hxs[s0 * 64 + lane], u1 = hxs[s1 * 64 + lane];
            uint u2 = hxs[s2 * 64 + lane], u3 = hxs[s3 * 64 + lane];
            uint u4 = hxs[s4 * 64 + lane], u5 = hxs[s5 * 64 + lane];
            uint u6 = hxs[s6 * 64 + lane], u7 = hxs[s7 * 64 + lane];
            a0 = fmaf(n0, bfl(u0), a0); a0 = fmaf(n1, bfl(u1), a0);
            a0 = fmaf(n2, bfl(u2), a0); a0 = fmaf(n3, bfl(u3), a0);
            a0 = fmaf(n4, bfl(u4), a0); a0 = fmaf(n5, bfl(u5), a0);
            a0 = fmaf(n6, bfl(u6), a0); a0 = fmaf(n7, bfl(u7), a0);
            a1 = fmaf(n0, bfh(u0), a1); a1 = fmaf(n1, bfh(u1), a1);
            a1 = fmaf(n2, bfh(u2), a1); a1 = fmaf(n3, bfh(u3), a1);
            a1 = fmaf(n4, bfh(u4), a1); a1 = fmaf(n5, bfh(u5), a1);
            a1 = fmaf(n6, bfh(u6), a1); a1 = fmaf(n7, bfh(u7), a1);
        }
        for (; i + 1 < e; i += 2) {
            int s0 = csr_src[i], s1 = csr_src[i + 1];
            float n0 = dinv[s0], n1 = dinv[s1];
            uint u0 = hxs[s0 * 64 + lane], u1 = hxs[s1 * 64 + lane];
            a0 = fmaf(n0, bfl(u0), a0); a0 = fmaf(n1, bfl(u1), a0);
            a1 = fmaf(n0, bfh(u0), a1); a1 = fmaf(n1, bfh(u1), a1);
        }
        if (i < e) {
            int s0 = csr_src[i];
            float n0 = dinv[s0];
            uint u0 = hxs[s0 * 64 + lane];
            a0 = fmaf(n0, bfl(u0), a0);
            a1 = fmaf(n0, bfh(u0), a1);
        }
        lds_h[(w * 4 + q) * 68 + lane] = packbf(fmaxf(fmaf(dv, a0, bb.x), 0.f),
                                                fmaxf(fmaf(dv, a1, bb.y), 0.f));
    }
    __syncthreads();

    if (w < 2) {   // waves 0,1: y[16 nodes][16 j] each (j-half = w)
        frag_cd acc = (frag_cd){0.f, 0.f, 0.f, 0.f};
#pragma unroll
        for (int c = 0; c < 4; c++) {   // k chunks of 32
            frag_ab a = *(const frag_ab*)&lds_h[lm * 68 + 16 * c + 4 * quad];
            frag_ab b = *(const frag_ab*)&w2t[(w * 16 + lm) * D_H + c * 32 + quad * 8];
            acc = __builtin_amdgcn_mfma_f32_16x16x32_bf16(a, b, acc, 0, 0, 0);
        }
#pragma unroll
        for (int r = 0; r < 4; r++) {
            int node = nbase + quad * 4 + r;
            float dv = dinv[node];
            hx2s[node * D_OUT + w * 16 + lm] = f2bf(acc[r] * dv);
        }
    }
}

// ---- layer-2 gather + bias + log_softmax: 16 lanes per node; 8-deep unroll.
__global__ __launch_bounds__(256, 8) void k_agg2(const uint* __restrict__ hx2s,
                                                 const int* __restrict__ csr_src,
                                                 const int* __restrict__ rp,
                                                 const int* __restrict__ deg,
                                                 const float* __restrict__ dinv,
                                                 const float* __restrict__ b2,
                                                 float2* __restrict__ out, int n) {
    int v = blockIdx.x * 16 + (threadIdx.x >> 4);
    if (v >= n) return;
    int l16 = threadIdx.x & 15;
    uint u = hx2s[v * 16 + l16];
    float a0 = bfl(u), a1 = bfh(u);
    int s = rp[v], e = s + deg[v];
    int i = s;
    for (; i + 7 < e; i += 8) {
        int s0 = csr_src[i], s1 = csr_src[i + 1];
        int s2 = csr_src[i + 2], s3 = csr_src[i + 3];
        int s4 = csr_src[i + 4], s5 = csr_src[i + 5];
        int s6 = csr_src[i + 6], s7 = csr_src[i + 7];
        uint u0 = hx2s[s0 * 16 + l16], u1 = hx2s[s1 * 16 + l16];
        uint u2 = hx2s[s2 * 16 + l16], u3 = hx2s[s3 * 16 + l16];
        uint u4 = hx2s[s4 * 16 + l16], u5 = hx2s[s5 * 16 + l16];
        uint u6 = hx2s[s6 * 16 + l16], u7 = hx2s[s7 * 16 + l16];
        a0 += bfl(u0) + bfl(u1) + bfl(u2) + bfl(u3) + bfl(u4) + bfl(u5) + bfl(u6) + bfl(u7);
        a1 += bfh(u0) + bfh(u1) + bfh(u2) + bfh(u3) + bfh(u4) + bfh(u5) + bfh(u6) + bfh(u7);
    }
    for (; i + 1 < e; i += 2) {
        int s0 = csr_src[i], s1 = csr_src[i + 1];
        uint u0 = hx2s[s0 * 16 + l16], u1 = hx2s[s1 * 16 + l16];
        a0 += bfl(u0) + bfl(u1);
        a1 += bfh(u0) + bfh(u1);
    }
    if (i < e) {
        uint u0 = hx2s[csr_src[i] * 16 + l16];
        a0 += bfl(u0);
        a1 += bfh(u0);
    }
    float dv = dinv[v];
    float2 bb = ((const float2*)b2)[l16];
    float t0 = fmaf(dv, a0, bb.x), t1 = fmaf(dv, a1, bb.y);
    float mx = fmaxf(t0, t1);
#pragma unroll
    for (int m = 8; m >= 1; m >>= 1) mx = fmaxf(mx, __shfl_xor(mx, m));
    float sum = __expf(t0 - mx) + __expf(t1 - mx);
#pragma unroll
    for (int m = 8; m >= 1; m >>= 1) sum += __shfl_xor(sum, m);
    float lse = mx + __logf(sum);
    out[v * 16 + l16] = make_float2(t0 - lse, t1 - lse);
}

extern "C" void kernel_launch(void* const* d_in, const int* in_sizes, int n_in,
                              void* d_out, int out_size, void* d_ws, size_t ws_size,
                              hipStream_t stream) {
    const float* x  = (const float*)d_in[0];
    const float* W1 = (const float*)d_in[1];
    const float* b1 = (const float*)d_in[2];
    const float* W2 = (const float*)d_in[3];
    const float* b2 = (const float*)d_in[4];
    const int*   ei = (const int*)d_in[5];
    const int* row = ei;
    const int* col = ei + N_EDGES;

    // ws layout (4B words): deg[N_PAD] | gcur[256] | rp[N_PAD] | dinv[N_PAD] |
    //   csr_src[NB*CAPB] | pairs[NB*CAPB] | w1t | w2t | hxs | (h unused) | hx2s
    int*    ws_i    = (int*)d_ws;
    int*    deg     = ws_i;
    int*    gcur    = ws_i + N_PAD;
    int*    rp      = ws_i + N_PAD + 256;
    float*  dinv    = (float*)(ws_i + 2 * N_PAD + 256);
    int*    csr_src = ws_i + 3 * N_PAD + 256;
    uint*   pairs   = (uint*)(csr_src + NB * CAPB);
    ushort* w1t     = (ushort*)(pairs + NB * CAPB);
    ushort* w2t     = w1t + D_IN * D_H;
    ushort* hxs     = w2t + D_H * D_OUT;
    ushort* h_unused= hxs + (ll)N_NODES * D_H;
    ushort* hx2s    = h_unused + (ll)N_NODES * D_H;

    const int n = N_NODES, e = N_EDGES;

    // zero gcur + pack weights (no deg memset needed: fillB writes deg itself)
    k_prep<<<(D_IN * D_H + D_H * D_OUT + 255) / 256, 256, 0, stream>>>(W1, W2, w1t, w2t, gcur);

    // bucket partition (blocks [0,GA)) + GEMM1 (blocks [GA,GA+GG)), co-resident,
    // contiguous split so both roles spread across all 8 XCDs.
    const int GA = (e + CHUNK - 1) / CHUNK;
    const int GG = (n + 127) / 128;
    k_fused<<<GA + GG, 256, 0, stream>>>(row, col, gcur, pairs, x, w1t, hxs, n, e);

    k_fillB<<<NB, 512, 0, stream>>>(pairs, gcur, deg, rp, dinv, csr_src, n);
    // agg1 + gemm2 fused: 16 nodes per block (100000 % 16 == 0 -> 6250 blocks)
    k_agg1f<<<n / 16, 256, 0, stream>>>((const uint*)hxs, csr_src, rp, deg, dinv, b1,
                                        w2t, hx2s, n);
    k_agg2<<<(n + 15) / 16, 256, 0, stream>>>((const uint*)hx2s, csr_src, rp, deg, dinv, b2,
                                              (float2*)d_out, n);
}

// Round 8
// 323.847 us; speedup vs baseline: 1.0927x; 1.0060x over previous
//
#include <hip/hip_runtime.h>
#include <math.h>

#define N_NODES 100000
#define N_EDGES 1600000
#define D_IN 256
#define D_H 128
#define D_OUT 32
#define N_PAD 102400
#define NB 196       // ceil(100000/512) buckets of 512 target nodes
#define CAPB 10240   // fixed capacity per bucket (mean 8163, +23 sigma)
#define CHUNK 4096   // edges per bucket-block -> 391 blocks

typedef long long ll;
typedef unsigned int uint;
typedef unsigned short ushort;
typedef unsigned char uchar;
typedef short frag_ab __attribute__((ext_vector_type(8)));   // 8 bf16
typedef float frag_cd __attribute__((ext_vector_type(4)));   // 4 f32

__device__ __forceinline__ ushort f2bf(float f) {            // RNE fp32->bf16
    uint u = __float_as_uint(f);
    u += 0x7FFFu + ((u >> 16) & 1u);
    return (ushort)(u >> 16);
}
__device__ __forceinline__ float bfl(uint u) { return __uint_as_float(u << 16); }
__device__ __forceinline__ float bfh(uint u) { return __uint_as_float(u & 0xFFFF0000u); }
__device__ __forceinline__ uint packbf(float a, float b) {
    return (uint)f2bf(a) | ((uint)f2bf(b) << 16);
}

// ---- tiny prep: zero gcur + transpose/pack weights
__global__ __launch_bounds__(256) void k_prep(const float* __restrict__ W1,
                                              const float* __restrict__ W2,
                                              ushort* __restrict__ w1t,
                                              ushort* __restrict__ w2t,
                                              int* __restrict__ gcur) {
    int gi = blockIdx.x * 256 + threadIdx.x;
    if (blockIdx.x == 0) gcur[threadIdx.x] = 0;   // 256 >= NB
    if (gi < D_IN * D_H) {
        int k = gi >> 7, nn = gi & 127;
        w1t[nn * D_IN + k] = f2bf(W1[gi]);
    } else if (gi < D_IN * D_H + D_H * D_OUT) {
        int j = gi - D_IN * D_H;
        int k = j >> 5, nn = j & 31;
        w2t[nn * D_H + k] = f2bf(W2[j]);
    }
}

// ---- ATTRIBUTION SPLIT (R8): partition alone. Exact R2-proven code — the
//      fused kernel's 93us is max(partition, GEMM1) under interference and 7
//      rounds of modeling failed to attribute it. Separate dispatch = separate
//      rocprof row. R4 lesson stands: no global-atomic variants.
__global__ __launch_bounds__(256, 3) void k_part(const int* __restrict__ row,
                                                 const int* __restrict__ col,
                                                 int* __restrict__ gcur,
                                                 uint* __restrict__ pairs, int e) {
    __shared__ int cnt[NB];      // counts, then phase-2 cursors
    __shared__ int lofs[NB];     // local sorted offsets
    __shared__ int lstart[NB];   // claimed global run starts
    __shared__ int sc[256];      // scan temp
    __shared__ uint spair[CHUNK];
    __shared__ uchar sbuck[CHUNK];
    const int t = threadIdx.x;
    const int bid = blockIdx.x;

    if (t < NB) cnt[t] = 0;
    __syncthreads();
    const int base = bid * CHUNK;
    const int end = min(base + CHUNK, e);
    const int valid = end - base;
    // cache this thread's (<=16) edges in registers; statically indexed
    int rs[16], cs[16];
#pragma unroll
    for (int j = 0; j < 16; j++) {
        int idx = base + t + j * 256;
        bool ok = idx < end;
        int c = ok ? col[idx] : 0;
        rs[j] = ok ? row[idx] : 0;
        cs[j] = ok ? c : -1;
        if (ok) atomicAdd(&cnt[c >> 9], 1);
    }
    __syncthreads();
    int v = (t < NB) ? cnt[t] : 0;
    sc[t] = v;
    __syncthreads();
    for (int o = 1; o < 256; o <<= 1) {
        int u2 = (t >= o) ? sc[t - o] : 0;
        __syncthreads();
        sc[t] += u2;
        __syncthreads();
    }
    if (t < NB) {
        lofs[t] = sc[t] - v;
        lstart[t] = (v > 0) ? atomicAdd(&gcur[t], v) : 0;
        cnt[t] = 0;  // reuse as local cursor
    }
    __syncthreads();
#pragma unroll
    for (int j = 0; j < 16; j++) {
        int c = cs[j];
        if (c >= 0) {
            int b = c >> 9;
            int pos = lofs[b] + atomicAdd(&cnt[b], 1);
            spair[pos] = ((uint)rs[j] << 9) | (uint)(c & 511);
            sbuck[pos] = (uchar)b;
        }
    }
    __syncthreads();
    for (int i = t; i < valid; i += 256) {   // bucket-contiguous coalesced emission
        int b = sbuck[i];
        int rel = lstart[b] + (i - lofs[b]);
        if (rel < CAPB) pairs[b * CAPB + rel] = spair[i];
    }
}

// ---- GEMM1 standalone (R0-proven): hxs = bf16( dinv * (x @ W1) ).
//      Runs AFTER fillB so dinv is available — agg1f then needs no per-edge
//      dinv loads (rows pre-scaled by dinv[src]).
__global__ __launch_bounds__(256, 3) void k_gemm1(const float* __restrict__ x,
                                                  const ushort* __restrict__ w1t,
                                                  const float* __restrict__ dinv,
                                                  ushort* __restrict__ hxs, int n) {
    const int t = threadIdx.x;
    const int wv = t >> 6, lane = t & 63;
    const int lm = lane & 15, quad = lane >> 4;
    const int base = blockIdx.x * 128 + wv * 32;

    frag_cd acc[2][8];
#pragma unroll
    for (int mt = 0; mt < 2; mt++)
#pragma unroll
        for (int nt = 0; nt < 8; nt++) acc[mt][nt] = (frag_cd){0.f, 0.f, 0.f, 0.f};

    const float4* xr[2];
#pragma unroll
    for (int mt = 0; mt < 2; mt++) {
        int node = base + mt * 16 + lm;
        xr[mt] = (const float4*)(x + (ll)min(node, n - 1) * D_IN);
    }

#pragma unroll
    for (int ks = 0; ks < 8; ks++) {
        frag_ab a[2];
#pragma unroll
        for (int mt = 0; mt < 2; mt++) {
            float4 v0 = xr[mt][ks * 8 + quad * 2];
            float4 v1 = xr[mt][ks * 8 + quad * 2 + 1];
            uint* ap = (uint*)&a[mt];
            ap[0] = packbf(v0.x, v0.y);
            ap[1] = packbf(v0.z, v0.w);
            ap[2] = packbf(v1.x, v1.y);
            ap[3] = packbf(v1.z, v1.w);
        }
#pragma unroll
        for (int nt = 0; nt < 8; nt++) {
            frag_ab b = *(const frag_ab*)&w1t[(nt * 16 + lm) * D_IN + ks * 32 + quad * 8];
#pragma unroll
            for (int mt = 0; mt < 2; mt++)
                acc[mt][nt] = __builtin_amdgcn_mfma_f32_16x16x32_bf16(
                    a[mt], b, acc[mt][nt], 0, 0, 0);
        }
    }

#pragma unroll
    for (int mt = 0; mt < 2; mt++) {
#pragma unroll
        for (int r = 0; r < 4; r++) {
            int node = base + mt * 16 + quad * 4 + r;
            if (node < n) {
                float dv = dinv[node];
#pragma unroll
                for (int nt = 0; nt < 8; nt++)
                    hxs[(ll)node * D_H + nt * 16 + lm] = f2bf(acc[mt][nt][r] * dv);
            }
        }
    }
}

// ---- pass B (R2-proven, 512 threads): LDS histogram reproduces deg, scan,
//      LDS-staged csr + coalesced write.
__global__ __launch_bounds__(512) void k_fillB(const uint* __restrict__ pairs,
                                               const int* __restrict__ gcur,
                                               int* __restrict__ deg,
                                               int* __restrict__ rp,
                                               float* __restrict__ dinv,
                                               int* __restrict__ csr_src, int n) {
    __shared__ int scsr[CAPB];   // 40 KB staged csr for this bucket
    __shared__ int hcnt[512];    // per-node in-degree (LDS histogram)
    __shared__ int cur[512];     // scatter cursors
    __shared__ int ssum[512];
    const int b = blockIdx.x, t = threadIdx.x;
    const int node0 = b << 9;
    hcnt[t] = 0;
    __syncthreads();
    const int cnt = min(gcur[b], CAPB);
    const uint* pr = pairs + b * CAPB;
    for (int i = t; i < cnt; i += 512) atomicAdd(&hcnt[pr[i] & 511], 1);
    __syncthreads();
    int d = hcnt[t];
    ssum[t] = d;
    __syncthreads();
    for (int o = 1; o < 512; o <<= 1) {
        int u2 = (t >= o) ? ssum[t - o] : 0;
        __syncthreads();
        ssum[t] += u2;
        __syncthreads();
    }
    int excl = ssum[t] - d;
    cur[t] = excl;
    {
        int vv = node0 + t;
        if (vv < n) {
            rp[vv] = b * CAPB + excl;
            deg[vv] = d;
            dinv[vv] = rsqrtf((float)(1 + d));
        }
    }
    __syncthreads();
    for (int i = t; i < cnt; i += 512) {
        uint pp = pr[i];
        int pos = atomicAdd(&cur[pp & 511], 1);
        if (pos < CAPB) scsr[pos] = (int)(pp >> 9);
    }
    __syncthreads();
    for (int i = t; i < cnt; i += 512)   // coalesced contiguous write
        csr_src[b * CAPB + i] = scsr[i];
}

// ---- layer-1 gather + FUSED layer-2 GEMM: block = 16 nodes (4 waves x 4 nodes).
//      hxs rows now pre-scaled by dinv[src] -> neighbor terms are plain adds
//      (no per-edge dinv loads). 8-deep unroll (R6: 16-deep thrashes L2).
__global__ __launch_bounds__(256, 8) void k_agg1f(const uint* __restrict__ hxs,
                                                  const int* __restrict__ csr_src,
                                                  const int* __restrict__ rp,
                                                  const int* __restrict__ deg,
                                                  const float* __restrict__ dinv,
                                                  const float* __restrict__ b1,
                                                  const ushort* __restrict__ w2t,
                                                  ushort* __restrict__ hx2s, int n) {
    __shared__ uint lds_h[16 * 68];   // 16 h-rows of 64 uints, stride 68 (bank-spread)
    const int t = threadIdx.x;
    const int w = t >> 6, lane = t & 63;
    const int lm = lane & 15, quad = lane >> 4;
    const int nbase = blockIdx.x * 16;

    float2 bb = ((const float2*)b1)[lane];
#pragma unroll
    for (int q = 0; q < 4; q++) {
        int v = nbase + w * 4 + q;
        float dv = dinv[v];
        uint u = hxs[v * 64 + lane];
        float a0 = bfl(u), a1 = bfh(u);   // self-loop term (row pre-scaled by dinv[v])
        int s = rp[v], e = s + deg[v];
        int i = s;
        for (; i + 7 < e; i += 8) {
            int s0 = csr_src[i], s1 = csr_src[i + 1];
            int s2 = csr_src[i + 2], s3 = csr_src[i + 3];
            int s4 = csr_src[i + 4], s5 = csr_src[i + 5];
            int s6 = csr_src[i + 6], s7 = csr_src[i + 7];
            uint u0 = hxs[s0 * 64 + lane], u1 = hxs[s1 * 64 + lane];
            uint u2 = hxs[s2 * 64 + lane], u3 = hxs[s3 * 64 + lane];
            uint u4 = hxs[s4 * 64 + lane], u5 = hxs[s5 * 64 + lane];
            uint u6 = hxs[s6 * 64 + lane], u7 = hxs[s7 * 64 + lane];
            a0 += bfl(u0) + bfl(u1) + bfl(u2) + bfl(u3) + bfl(u4) + bfl(u5) + bfl(u6) + bfl(u7);
            a1 += bfh(u0) + bfh(u1) + bfh(u2) + bfh(u3) + bfh(u4) + bfh(u5) + bfh(u6) + bfh(u7);
        }
        for (; i + 1 < e; i += 2) {
            int s0 = csr_src[i], s1 = csr_src[i + 1];
            uint u0 = hxs[s0 * 64 + lane], u1 = hxs[s1 * 64 + lane];
            a0 += bfl(u0) + bfl(u1);
            a1 += bfh(u0) + bfh(u1);
        }
        if (i < e) {
            uint u0 = hxs[csr_src[i] * 64 + lane];
            a0 += bfl(u0);
            a1 += bfh(u0);
        }
        lds_h[(w * 4 + q) * 68 + lane] = packbf(fmaxf(fmaf(dv, a0, bb.x), 0.f),
                                                fmaxf(fmaf(dv, a1, bb.y), 0.f));
    }
    __syncthreads();

    if (w < 2) {   // waves 0,1: y[16 nodes][16 j] each (j-half = w)
        frag_cd acc = (frag_cd){0.f, 0.f, 0.f, 0.f};
#pragma unroll
        for (int c = 0; c < 4; c++) {   // k chunks of 32
            frag_ab a = *(const frag_ab*)&lds_h[lm * 68 + 16 * c + 4 * quad];
            frag_ab b = *(const frag_ab*)&w2t[(w * 16 + lm) * D_H + c * 32 + quad * 8];
            acc = __builtin_amdgcn_mfma_f32_16x16x32_bf16(a, b, acc, 0, 0, 0);
        }
#pragma unroll
        for (int r = 0; r < 4; r++) {
            int node = nbase + quad * 4 + r;
            float dv = dinv[node];
            hx2s[node * D_OUT + w * 16 + lm] = f2bf(acc[r] * dv);
        }
    }
}

// ---- layer-2 gather + bias + log_softmax: 16 lanes per node; 8-deep unroll.
__global__ __launch_bounds__(256, 8) void k_agg2(const uint* __restrict__ hx2s,
                                                 const int* __restrict__ csr_src,
                                                 const int* __restrict__ rp,
                                                 const int* __restrict__ deg,
                                                 const float* __restrict__ dinv,
                                                 const float* __restrict__ b2,
                                                 float2* __restrict__ out, int n) {
    int v = blockIdx.x * 16 + (threadIdx.x >> 4);
    if (v >= n) return;
    int l16 = threadIdx.x & 15;
    uint u = hx2s[v * 16 + l16];
    float a0 = bfl(u), a1 = bfh(u);
    int s = rp[v], e = s + deg[v];
    int i = s;
    for (; i + 7 < e; i += 8) {
        int s0 = csr_src[i], s1 = csr_src[i + 1];
        int s2 = csr_src[i + 2], s3 = csr_src[i + 3];
        int s4 = csr_src[i + 4], s5 = csr_src[i + 5];
        int s6 = csr_src[i + 6], s7 = csr_src[i + 7];
        uint u0 = hx2s[s0 * 16 + l16], u1 = hx2s[s1 * 16 + l16];
        uint u2 = hx2s[s2 * 16 + l16], u3 = hx2s[s3 * 16 + l16];
        uint u4 = hx2s[s4 * 16 + l16], u5 = hx2s[s5 * 16 + l16];
        uint u6 = hx2s[s6 * 16 + l16], u7 = hx2s[s7 * 16 + l16];
        a0 += bfl(u0) + bfl(u1) + bfl(u2) + bfl(u3) + bfl(u4) + bfl(u5) + bfl(u6) + bfl(u7);
        a1 += bfh(u0) + bfh(u1) + bfh(u2) + bfh(u3) + bfh(u4) + bfh(u5) + bfh(u6) + bfh(u7);
    }
    for (; i + 1 < e; i += 2) {
        int s0 = csr_src[i], s1 = csr_src[i + 1];
        uint u0 = hx2s[s0 * 16 + l16], u1 = hx2s[s1 * 16 + l16];
        a0 += bfl(u0) + bfl(u1);
        a1 += bfh(u0) + bfh(u1);
    }
    if (i < e) {
        uint u0 = hx2s[csr_src[i] * 16 + l16];
        a0 += bfl(u0);
        a1 += bfh(u0);
    }
    float dv = dinv[v];
    float2 bb = ((const float2*)b2)[l16];
    float t0 = fmaf(dv, a0, bb.x), t1 = fmaf(dv, a1, bb.y);
    float mx = fmaxf(t0, t1);
#pragma unroll
    for (int m = 8; m >= 1; m >>= 1) mx = fmaxf(mx, __shfl_xor(mx, m));
    float sum = __expf(t0 - mx) + __expf(t1 - mx);
#pragma unroll
    for (int m = 8; m >= 1; m >>= 1) sum += __shfl_xor(sum, m);
    float lse = mx + __logf(sum);
    out[v * 16 + l16] = make_float2(t0 - lse, t1 - lse);
}

extern "C" void kernel_launch(void* const* d_in, const int* in_sizes, int n_in,
                              void* d_out, int out_size, void* d_ws, size_t ws_size,
                              hipStream_t stream) {
    const float* x  = (const float*)d_in[0];
    const float* W1 = (const float*)d_in[1];
    const float* b1 = (const float*)d_in[2];
    const float* W2 = (const float*)d_in[3];
    const float* b2 = (const float*)d_in[4];
    const int*   ei = (const int*)d_in[5];
    const int* row = ei;
    const int* col = ei + N_EDGES;

    // ws layout (4B words): deg[N_PAD] | gcur[256] | rp[N_PAD] | dinv[N_PAD] |
    //   csr_src[NB*CAPB] | pairs[NB*CAPB] | w1t | w2t | hxs | (spare) | hx2s
    int*    ws_i    = (int*)d_ws;
    int*    deg     = ws_i;
    int*    gcur    = ws_i + N_PAD;
    int*    rp      = ws_i + N_PAD + 256;
    float*  dinv    = (float*)(ws_i + 2 * N_PAD + 256);
    int*    csr_src = ws_i + 3 * N_PAD + 256;
    uint*   pairs   = (uint*)(csr_src + NB * CAPB);
    ushort* w1t     = (ushort*)(pairs + NB * CAPB);
    ushort* w2t     = w1t + D_IN * D_H;
    ushort* hxs     = w2t + D_H * D_OUT;
    ushort* spare   = hxs + (ll)N_NODES * D_H;
    ushort* hx2s    = spare + (ll)N_NODES * D_H;

    const int n = N_NODES, e = N_EDGES;

    // zero gcur + pack weights
    k_prep<<<(D_IN * D_H + D_H * D_OUT + 255) / 256, 256, 0, stream>>>(W1, W2, w1t, w2t, gcur);

    // ATTRIBUTION SPLIT: partition and GEMM1 as separate dispatches.
    const int GA = (e + CHUNK - 1) / CHUNK;
    k_part<<<GA, 256, 0, stream>>>(row, col, gcur, pairs, e);
    k_fillB<<<NB, 512, 0, stream>>>(pairs, gcur, deg, rp, dinv, csr_src, n);
    // GEMM1 after fillB: dinv available -> hxs rows pre-scaled by dinv[src].
    k_gemm1<<<(n + 127) / 128, 256, 0, stream>>>(x, w1t, dinv, hxs, n);
    // agg1 + gemm2 fused: 16 nodes per block (100000 % 16 == 0 -> 6250 blocks)
    k_agg1f<<<n / 16, 256, 0, stream>>>((const uint*)hxs, csr_src, rp, deg, dinv, b1,
                                        w2t, hx2s, n);
    k_agg2<<<(n + 15) / 16, 256, 0, stream>>>((const uint*)hx2s, csr_src, rp, deg, dinv, b2,
                                              (float2*)d_out, n);
}